// Round 6
// baseline (268.894 us; speedup 1.0000x reference)
//
#include <hip/hip_runtime.h>

#define NPTS 8192
#define KC   128
#define IFD  64
#define DL1  64
#define DL2  64
#define DL3  128
#define SPLITS 8
#define PPB  (NPTS/SPLITS)   // 1024 points per block (group_mlp)

#define FOR16(F) F(0) F(1) F(2) F(3) F(4) F(5) F(6) F(7) \
                 F(8) F(9) F(10) F(11) F(12) F(13) F(14) F(15)

// ---------------------------------------------------------------------------
// Kernel 1 (fused): block 0 = farthest point sampling (serial-latency-optimized)
//                   blocks 1..1024 = F1 = features @ W1[3:] + b1  (independent)
// ---------------------------------------------------------------------------
__global__ __launch_bounds__(512, 2) void fps_feat_kernel(
    const float* __restrict__ coords,
    const float* __restrict__ features,
    const float* __restrict__ W1,
    const float* __restrict__ b1,
    float* __restrict__ centers,
    float* __restrict__ F1) {
    const int tid = threadIdx.x;

    if (blockIdx.x != 0) {
        // ---- feature GEMM path: F1[p][d] = b1[d] + features[p] . W1[3:,d] ----
        const int d = tid & 63;
        const int p = (int)(blockIdx.x - 1) * 8 + (tid >> 6);
        float acc = b1[d];
        const float* frow = features + p * IFD;
#pragma unroll 8
        for (int a = 0; a < IFD; ++a) {
            acc += frow[a] * W1[(3 + a) * DL1 + d];
        }
        F1[p * DL1 + d] = acc;
        return;
    }

    // ---- FPS path: single block, 512 threads, 16 points/thread in registers --
    // R4/R5 evidence: VGPR_Count=48 (< 64 floats of state), dur identical across
    // alloca vs named-scalar forms -> backend REMATERIALIZES the loop-invariant
    // coords loads into the loop (96 KB/iter from L2 ~= the whole cost).
    // volatile outlaws the remat (exactly-once load semantics); asm pins insure
    // the values sit in VGPRs at loop entry.
    {
#pragma clang fp contract(off)
        const volatile float* vcoords = coords;   // forbid load sinking/remat
#define FPS_DECL(i) float x##i, y##i, z##i, d##i = 1e10f;
        FOR16(FPS_DECL)
#define FPS_LOAD(i) { const int n = i * 512 + tid;  \
                      x##i = vcoords[n * 3 + 0];    \
                      y##i = vcoords[n * 3 + 1];    \
                      z##i = vcoords[n * 3 + 2]; }
        FOR16(FPS_LOAD)
#define FPS_PIN(i) asm volatile("" : "+v"(x##i), "+v"(y##i), "+v"(z##i), "+v"(d##i));
        FOR16(FPS_PIN)

        __shared__ float wv[2][8];   // per-wave max value, double-buffered
        __shared__ int   widx[2];    // argmax index (atomicMin), double-buffered

        if (tid == 0) { widx[0] = 0x7FFFFFFF; widx[1] = 0x7FFFFFFF; }

        float cx = coords[0], cy = coords[1], cz = coords[2];
        if (tid == 0) { centers[0] = cx; centers[1] = cy; centers[2] = cz; }
        __syncthreads();

        for (int s = 1; s < KC; ++s) {
            const int buf = s & 1;
            // --- distance update + value-only max (10 VALU ops / point) ---
            float bv = -1.0f;
#define FPS_UPD(i) { const float dx = x##i - cx;              \
                     const float dy = y##i - cy;              \
                     const float dz = z##i - cz;              \
                     const float t2 = (dx * dx + dy * dy) + dz * dz; \
                     d##i = d##i < t2 ? d##i : t2;            \
                     bv = fmaxf(bv, d##i); }
            FOR16(FPS_UPD)
            // --- wave value-max reduce (max is exactly associative) ---
#pragma unroll
            for (int off = 32; off > 0; off >>= 1) {
                bv = fmaxf(bv, __shfl_down(bv, off));
            }
            if ((tid & 63) == 0) wv[buf][tid >> 6] = bv;
            __syncthreads();                       // barrier 1
            // --- all threads merge the 8 wave maxima ---
            float gv = wv[buf][0];
#pragma unroll
            for (int w = 1; w < 8; ++w) gv = fmaxf(gv, wv[buf][w]);
            // --- index recovery: lowest global index with dist == gv ---
            int ln = 0x7FFFFFFF;
#define FPS_CHK(i) if (d##i == gv) ln = min(ln, i * 512 + tid);
            FOR16(FPS_CHK)
            if (ln != 0x7FFFFFFF) atomicMin(&widx[buf], ln);
            __syncthreads();                       // barrier 2
            const int w = widx[buf];
            if (tid == 0) widx[buf ^ 1] = 0x7FFFFFFF;  // re-arm other buffer
            // --- uniform broadcast load of the winner's coords ---
            cx = coords[w * 3 + 0];
            cy = coords[w * 3 + 1];
            cz = coords[w * 3 + 2];
            if (tid == 0) {
                centers[s * 3 + 0] = cx;
                centers[s * 3 + 1] = cy;
                centers[s * 3 + 2] = cz;
            }
        }
    }
}

// ---------------------------------------------------------------------------
// Kernel 2: per-center ball query + MLP + masked max  (unchanged)
// grid = KC * SPLITS blocks of 256 threads; block handles PPB points of 1 center
// ---------------------------------------------------------------------------
__global__ __launch_bounds__(256) void group_mlp_kernel(
    const float* __restrict__ coords,
    const float* __restrict__ F1,
    const float* __restrict__ W1,   // rows 0..2 = rel part
    const float* __restrict__ W2,
    const float* __restrict__ b2,
    const float* __restrict__ W3,
    const float* __restrict__ b3,
    const float* __restrict__ centers,
    float* __restrict__ outf) {
    __shared__ float sW1r[3 * 64];
    __shared__ float sb2[64];
    __shared__ float sb3[128];
    __shared__ unsigned short list[PPB];
    __shared__ int cnt;
    __shared__ float h1[64 * 65];       // [point][dim], pad 65
    __shared__ float h2T[64 * 68];      // [dim][point], pad 68 (16B-aligned rows)
    __shared__ float red[8 * 128];

    const int tid = threadIdx.x;
    const int c = blockIdx.x >> 3;      // center id (SPLITS == 8)
    const int split = blockIdx.x & 7;
    const int base = split * PPB;

    if (tid < 192) sW1r[tid] = W1[tid];
    if (tid < 64)  sb2[tid] = b2[tid];
    if (tid < 128) sb3[tid] = b3[tid];
    if (tid == 0)  cnt = 0;
    const float cx = centers[c * 3 + 0];
    const float cy = centers[c * 3 + 1];
    const float cz = centers[c * 3 + 2];
    __syncthreads();

    // ---- ball-query compaction over this block's slice ----
    {
#pragma clang fp contract(off)
        for (int j = tid; j < PPB; j += 256) {
            const int n = base + j;
            const float dx = coords[n * 3 + 0] - cx;
            const float dy = coords[n * 3 + 1] - cy;
            const float dz = coords[n * 3 + 2] - cz;
            const float d2 = (dx * dx + dy * dy) + dz * dz;
            if (sqrtf(d2) < 1.0f) {
                const int pos = atomicAdd(&cnt, 1);
                list[pos] = (unsigned short)n;
            }
        }
    }
    __syncthreads();
    const int count = cnt;

    if (count > 0) {
        float rmax[4] = {0.f, 0.f, 0.f, 0.f};
        const int ntiles = (count + 63) >> 6;
        for (int T = 0; T < ntiles; ++T) {
            // ---- h1: [64 pts][64 dims], thread = (prow, d) ----
            {
                const int d = tid & 63;
                const int prow = tid >> 6;
#pragma unroll
                for (int r = 0; r < 16; ++r) {
                    const int p = r * 4 + prow;
                    const int li = T * 64 + p;
                    const int n = (li < count) ? (int)list[li] : (int)list[0];
                    const float rx = coords[n * 3 + 0] - cx;
                    const float ry = coords[n * 3 + 1] - cy;
                    const float rz = coords[n * 3 + 2] - cz;
                    float v = F1[n * DL1 + d];
                    v += rx * sW1r[d] + ry * sW1r[64 + d] + rz * sW1r[128 + d];
                    h1[p * 65 + d] = v > 0.f ? v : 0.f;
                }
            }
            __syncthreads();
            // ---- h2: 4x4 register blocks, output stored transposed ----
            {
                const int pblk = tid & 15;
                const int dblk = tid >> 4;
                const int p0 = pblk * 4;
                const int d0 = dblk * 4;
                float acc[4][4];
#pragma unroll
                for (int a = 0; a < 4; ++a)
#pragma unroll
                    for (int b = 0; b < 4; ++b) acc[a][b] = sb2[d0 + b];
                for (int i = 0; i < 64; ++i) {
                    float hv[4];
#pragma unroll
                    for (int a = 0; a < 4; ++a) hv[a] = h1[(p0 + a) * 65 + i];
                    const float4 w = *reinterpret_cast<const float4*>(&W2[i * DL2 + d0]);
#pragma unroll
                    for (int a = 0; a < 4; ++a) {
                        acc[a][0] += hv[a] * w.x;
                        acc[a][1] += hv[a] * w.y;
                        acc[a][2] += hv[a] * w.z;
                        acc[a][3] += hv[a] * w.w;
                    }
                }
#pragma unroll
                for (int b = 0; b < 4; ++b) {
                    float4 v;
                    v.x = fmaxf(acc[0][b], 0.f);
                    v.y = fmaxf(acc[1][b], 0.f);
                    v.z = fmaxf(acc[2][b], 0.f);
                    v.w = fmaxf(acc[3][b], 0.f);
                    *reinterpret_cast<float4*>(&h2T[(d0 + b) * 68 + p0]) = v;
                }
            }
            __syncthreads();
            // ---- h3: 8x4 register blocks + running max ----
            {
                const int dblk = tid & 31;
                const int pblk = tid >> 5;
                const int d0 = dblk * 4;
                const int p0 = pblk * 8;
                float acc[8][4];
#pragma unroll
                for (int p = 0; p < 8; ++p)
#pragma unroll
                    for (int b = 0; b < 4; ++b) acc[p][b] = sb3[d0 + b];
                for (int i = 0; i < 64; ++i) {
                    const float4 ha = *reinterpret_cast<const float4*>(&h2T[i * 68 + p0]);
                    const float4 hb = *reinterpret_cast<const float4*>(&h2T[i * 68 + p0 + 4]);
                    const float4 w = *reinterpret_cast<const float4*>(&W3[i * DL3 + d0]);
                    const float hv[8] = {ha.x, ha.y, ha.z, ha.w, hb.x, hb.y, hb.z, hb.w};
#pragma unroll
                    for (int p = 0; p < 8; ++p) {
                        acc[p][0] += hv[p] * w.x;
                        acc[p][1] += hv[p] * w.y;
                        acc[p][2] += hv[p] * w.z;
                        acc[p][3] += hv[p] * w.w;
                    }
                }
#pragma unroll
                for (int b = 0; b < 4; ++b) {
                    float m = acc[0][b];
#pragma unroll
                    for (int p = 1; p < 8; ++p) m = fmaxf(m, acc[p][b]);
                    m = fmaxf(m, 0.f);                 // relu (commutes with max)
                    rmax[b] = fmaxf(rmax[b], m);
                }
            }
            __syncthreads();
        }
        // ---- block reduce over the 8 point-groups, then global atomic max ----
        {
            const int dblk = tid & 31;
            const int pblk = tid >> 5;
            const int d0 = dblk * 4;
#pragma unroll
            for (int b = 0; b < 4; ++b) red[pblk * 128 + d0 + b] = rmax[b];
        }
        __syncthreads();
        if (tid < 128) {
            float m = red[tid];
#pragma unroll
            for (int r = 1; r < 8; ++r) m = fmaxf(m, red[r * 128 + tid]);
            atomicMax((int*)&outf[c * 128 + tid], __float_as_int(m));
        }
    }
}

// ---------------------------------------------------------------------------
extern "C" void kernel_launch(void* const* d_in, const int* in_sizes, int n_in,
                              void* d_out, int out_size, void* d_ws, size_t ws_size,
                              hipStream_t stream) {
    (void)in_sizes; (void)n_in; (void)ws_size;
    const float* coords   = (const float*)d_in[0];
    const float* features = (const float*)d_in[1];
    const float* W1 = (const float*)d_in[2];
    const float* b1 = (const float*)d_in[3];
    const float* W2 = (const float*)d_in[4];
    const float* b2 = (const float*)d_in[5];
    const float* W3 = (const float*)d_in[6];
    const float* b3 = (const float*)d_in[7];
    float* out = (float*)d_out;
    float* F1  = (float*)d_ws;   // 8192*64 floats = 2 MB scratch

    // out is re-poisoned before every launch; zero it (atomicMax identity, and
    // relu(h3) >= 0 so 0 is a safe floor matching max-over-nonempty-group).
    (void)hipMemsetAsync(d_out, 0, (size_t)out_size * sizeof(float), stream);

    // block 0: FPS (single CU, serial); blocks 1..1024: F1 precompute (other CUs)
    fps_feat_kernel<<<1 + NPTS / 8, 512, 0, stream>>>(coords, features, W1, b1,
                                                      out, F1);
    group_mlp_kernel<<<KC * SPLITS, 256, 0, stream>>>(coords, F1, W1, W2, b2, W3, b3,
                                                      out, out + KC * 3);
}

// Round 7
// 237.225 us; speedup vs baseline: 1.1335x; 1.1335x over previous
//
#include <hip/hip_runtime.h>

#define NPTS 8192
#define KC   128
#define IFD  64
#define DL1  64
#define DL2  64
#define DL3  128
#define SPLITS 8
#define PPB  (NPTS/SPLITS)   // 1024 points per task slice
#define NTASK (KC*SPLITS)    // 1024 (center, slice) tasks
#define FPT  16              // FPS points per thread (512 threads)

// ---------------------------------------------------------------------------
// Kernel A: F1[n][d] = b1[d] + features[n] . W1[3:,d]   (center-independent)
// ---------------------------------------------------------------------------
__global__ __launch_bounds__(256) void f1_kernel(const float* __restrict__ features,
                                                 const float* __restrict__ W1,
                                                 const float* __restrict__ b1,
                                                 float* __restrict__ F1) {
    const int tid = threadIdx.x;
    const int d = tid & 63;
    const int p = (int)blockIdx.x * 4 + (tid >> 6);
    float acc = b1[d];
    const float* frow = features + p * IFD;
#pragma unroll 8
    for (int a = 0; a < IFD; ++a) {
        acc += frow[a] * W1[(3 + a) * DL1 + d];
    }
    F1[p * DL1 + d] = acc;
}

// ---------------------------------------------------------------------------
// Kernel B (fused, producer-consumer): grid = 256 blocks x 512 thr, ALL resident
//   block 0      : FPS producer — publishes centers via device-scope atomicExch
//   blocks 1..255: consumers — static tasks t=(b-1)+255k, poll center, run
//                  ball-query + 3-layer MLP + masked max for that slice
// waves_per_eu(2,2): caps regalloc occupancy target at 2 waves/EU -> 256-VGPR
// budget; R4-R6 showed the default targets 8 waves/EU (64 VGPR) and spills the
// 64-float FPS state (VGPR_Count stuck at 48, ~2830 cyc/iter of L1/L2 traffic).
// ---------------------------------------------------------------------------
__global__ __attribute__((amdgpu_flat_work_group_size(512, 512),
                          amdgpu_waves_per_eu(2, 2)))
void fused_kernel(const float* __restrict__ coords,
                  const float* __restrict__ F1,
                  const float* __restrict__ W1,   // rows 0..2 = rel part
                  const float* __restrict__ W2,
                  const float* __restrict__ b2,
                  const float* __restrict__ W3,
                  const float* __restrict__ b3,
                  float* centers,                  // d_out, atomically published
                  float* __restrict__ outf) {
    __shared__ float sW1r[3 * 64];
    __shared__ float sb2[64];
    __shared__ float sb3[128];
    __shared__ unsigned short list[PPB];
    __shared__ int cnt;
    __shared__ float scc[3];
    __shared__ float h1[64 * 65];       // [point][dim], pad 65
    __shared__ float h2T[64 * 68];      // [dim][point], pad 68
    __shared__ float red[16 * 128];
    __shared__ float wv[2][8];          // FPS per-wave maxima (double-buffered)
    __shared__ int   widx[2];           // FPS argmin-index (double-buffered)

    const int tid = threadIdx.x;

    if (blockIdx.x == 0) {
        // ================= FPS producer =================
        {
#pragma clang fp contract(off)
            float px[FPT], py[FPT], pz[FPT], dist[FPT];
#pragma unroll
            for (int i = 0; i < FPT; ++i) {
                const int n = i * 512 + tid;
                px[i] = coords[n * 3 + 0];
                py[i] = coords[n * 3 + 1];
                pz[i] = coords[n * 3 + 2];
                dist[i] = 1e10f;
            }
            if (tid == 0) { widx[0] = 0x7FFFFFFF; widx[1] = 0x7FFFFFFF; }

            float cx = coords[0], cy = coords[1], cz = coords[2];
            if (tid == 0) {
                atomicExch(&centers[0], cx);   // publish center 0 (device-coherent)
                atomicExch(&centers[1], cy);
                atomicExch(&centers[2], cz);
            }
            __syncthreads();

            for (int s = 1; s < KC; ++s) {
                const int buf = s & 1;
                float bv = -1.0f;
#pragma unroll
                for (int i = 0; i < FPT; ++i) {
                    const float dx = px[i] - cx;
                    const float dy = py[i] - cy;
                    const float dz = pz[i] - cz;
                    const float t2 = (dx * dx + dy * dy) + dz * dz;
                    const float dm = dist[i] < t2 ? dist[i] : t2;
                    dist[i] = dm;
                    bv = fmaxf(bv, dm);
                }
#pragma unroll
                for (int off = 32; off > 0; off >>= 1) {
                    bv = fmaxf(bv, __shfl_down(bv, off));
                }
                if ((tid & 63) == 0) wv[buf][tid >> 6] = bv;
                __syncthreads();                       // barrier 1
                float gv = wv[buf][0];
#pragma unroll
                for (int w = 1; w < 8; ++w) gv = fmaxf(gv, wv[buf][w]);
                int ln = 0x7FFFFFFF;
#pragma unroll
                for (int i = 0; i < FPT; ++i) {
                    if (dist[i] == gv) ln = min(ln, i * 512 + tid);
                }
                if (ln != 0x7FFFFFFF) atomicMin(&widx[buf], ln);
                __syncthreads();                       // barrier 2
                const int w = widx[buf];
                if (tid == 0) widx[buf ^ 1] = 0x7FFFFFFF;
                cx = coords[w * 3 + 0];
                cy = coords[w * 3 + 1];
                cz = coords[w * 3 + 2];
                if (tid == 0) {
                    atomicExch(&centers[s * 3 + 0], cx);   // publish (fire-and-forget)
                    atomicExch(&centers[s * 3 + 1], cy);
                    atomicExch(&centers[s * 3 + 2], cz);
                }
            }
        }
        return;
    }

    // ================= MLP consumer =================
    if (tid < 192) sW1r[tid] = W1[tid];
    if (tid < 64)  sb2[tid] = b2[tid];
    if (tid < 128) sb3[tid] = b3[tid];
    __syncthreads();

    for (int k = 0;; ++k) {
        const int t = (int)(blockIdx.x - 1) + 255 * k;   // static task map, covers 0..1023
        if (t >= NTASK) break;
        const int c = t >> 3;
        const int base = (t & 7) * PPB;

        if (tid == 0) {
            float x, y, z;
            for (;;) {   // center ready <=> all three coords nonzero (normal data)
                x = atomicAdd(&centers[c * 3 + 0], 0.0f);
                y = atomicAdd(&centers[c * 3 + 1], 0.0f);
                z = atomicAdd(&centers[c * 3 + 2], 0.0f);
                if (x != 0.0f && y != 0.0f && z != 0.0f) break;
                __builtin_amdgcn_s_sleep(8);
            }
            scc[0] = x; scc[1] = y; scc[2] = z; cnt = 0;
        }
        __syncthreads();
        const float cx = scc[0], cy = scc[1], cz = scc[2];

        // ---- ball-query compaction over this task's slice ----
        {
#pragma clang fp contract(off)
            for (int j = tid; j < PPB; j += 512) {
                const int n = base + j;
                const float dx = coords[n * 3 + 0] - cx;
                const float dy = coords[n * 3 + 1] - cy;
                const float dz = coords[n * 3 + 2] - cz;
                const float d2 = (dx * dx + dy * dy) + dz * dz;
                if (sqrtf(d2) < 1.0f) {
                    const int pos = atomicAdd(&cnt, 1);
                    list[pos] = (unsigned short)n;
                }
            }
        }
        __syncthreads();
        const int count = cnt;   // uniform; may be 0 for some slices (ok: another
                                 // slice of c contains the center point itself)
        if (count > 0) {
            float rmax[4] = {0.f, 0.f, 0.f, 0.f};
            const int ntiles = (count + 63) >> 6;
            for (int T = 0; T < ntiles; ++T) {
                // ---- h1: 64 pts x 64 dims; thread = (d, prow), 8 rows each ----
                {
                    const int d = tid & 63;
                    const int pr = tid >> 6;
#pragma unroll
                    for (int r = 0; r < 8; ++r) {
                        const int p = r * 8 + pr;
                        const int li = T * 64 + p;
                        const int n = (li < count) ? (int)list[li] : (int)list[0];
                        const float rx = coords[n * 3 + 0] - cx;
                        const float ry = coords[n * 3 + 1] - cy;
                        const float rz = coords[n * 3 + 2] - cz;
                        float v = F1[n * DL1 + d];
                        v += rx * sW1r[d] + ry * sW1r[64 + d] + rz * sW1r[128 + d];
                        h1[p * 65 + d] = v > 0.f ? v : 0.f;
                    }
                }
                __syncthreads();
                // ---- h2: 2x4 register blocks, stored transposed ----
                {
                    const int p0 = (tid & 31) * 2;
                    const int d0 = (tid >> 5) * 4;
                    float acc[2][4];
#pragma unroll
                    for (int a = 0; a < 2; ++a)
#pragma unroll
                        for (int j = 0; j < 4; ++j) acc[a][j] = sb2[d0 + j];
                    for (int i = 0; i < 64; ++i) {
                        const float h0 = h1[p0 * 65 + i];
                        const float hA = h1[(p0 + 1) * 65 + i];
                        const float4 w = *reinterpret_cast<const float4*>(&W2[i * DL2 + d0]);
                        acc[0][0] += h0 * w.x; acc[0][1] += h0 * w.y;
                        acc[0][2] += h0 * w.z; acc[0][3] += h0 * w.w;
                        acc[1][0] += hA * w.x; acc[1][1] += hA * w.y;
                        acc[1][2] += hA * w.z; acc[1][3] += hA * w.w;
                    }
#pragma unroll
                    for (int j = 0; j < 4; ++j) {
                        h2T[(d0 + j) * 68 + p0]     = fmaxf(acc[0][j], 0.f);
                        h2T[(d0 + j) * 68 + p0 + 1] = fmaxf(acc[1][j], 0.f);
                    }
                }
                __syncthreads();
                // ---- h3: 4x4 register blocks + running max ----
                {
                    const int p0 = (tid >> 5) * 4;
                    const int d0 = (tid & 31) * 4;
                    float acc[4][4];
#pragma unroll
                    for (int p = 0; p < 4; ++p)
#pragma unroll
                        for (int j = 0; j < 4; ++j) acc[p][j] = sb3[d0 + j];
                    for (int i = 0; i < 64; ++i) {
                        const float4 hv = *reinterpret_cast<const float4*>(&h2T[i * 68 + p0]);
                        const float4 w = *reinterpret_cast<const float4*>(&W3[i * DL3 + d0]);
                        const float hh[4] = {hv.x, hv.y, hv.z, hv.w};
#pragma unroll
                        for (int p = 0; p < 4; ++p) {
                            acc[p][0] += hh[p] * w.x;
                            acc[p][1] += hh[p] * w.y;
                            acc[p][2] += hh[p] * w.z;
                            acc[p][3] += hh[p] * w.w;
                        }
                    }
#pragma unroll
                    for (int j = 0; j < 4; ++j) {
                        float m = acc[0][j];
#pragma unroll
                        for (int p = 1; p < 4; ++p) m = fmaxf(m, acc[p][j]);
                        m = fmaxf(m, 0.f);                 // relu commutes with max
                        rmax[j] = fmaxf(rmax[j], m);
                    }
                }
                __syncthreads();
            }
            // ---- reduce over the 16 point-groups, one atomicMax per dim ----
            {
                const int pg = tid >> 5;
                const int d0 = (tid & 31) * 4;
#pragma unroll
                for (int j = 0; j < 4; ++j) red[pg * 128 + d0 + j] = rmax[j];
            }
            __syncthreads();
            if (tid < 128) {
                float m = red[tid];
#pragma unroll
                for (int pg = 1; pg < 16; ++pg) m = fmaxf(m, red[pg * 128 + tid]);
                atomicMax((int*)&outf[c * 128 + tid], __float_as_int(m));
            }
        }
        // next task's first barrier (after scc/cnt write) orders list/red reuse
    }
}

// ---------------------------------------------------------------------------
extern "C" void kernel_launch(void* const* d_in, const int* in_sizes, int n_in,
                              void* d_out, int out_size, void* d_ws, size_t ws_size,
                              hipStream_t stream) {
    (void)in_sizes; (void)n_in; (void)ws_size;
    const float* coords   = (const float*)d_in[0];
    const float* features = (const float*)d_in[1];
    const float* W1 = (const float*)d_in[2];
    const float* b1 = (const float*)d_in[3];
    const float* W2 = (const float*)d_in[4];
    const float* b2 = (const float*)d_in[5];
    const float* W3 = (const float*)d_in[6];
    const float* b3 = (const float*)d_in[7];
    float* out = (float*)d_out;
    float* F1  = (float*)d_ws;   // 8192*64 floats = 2 MB scratch

    // Zero d_out: atomicMax identity for out_features (all >= 0 after relu),
    // and the "center not yet published" sentinel for the consumer poll.
    (void)hipMemsetAsync(d_out, 0, (size_t)out_size * sizeof(float), stream);

    f1_kernel<<<NPTS / 4, 256, 0, stream>>>(features, W1, b1, F1);
    fused_kernel<<<256, 512, 0, stream>>>(coords, F1, W1, W2, b2, W3, b3,
                                          out, out + KC * 3);
}